// Round 21
// baseline (35.515 us; speedup 1.0000x reference)
//
#include <hip/hip_runtime.h>

typedef __attribute__((ext_vector_type(8)))  short short8;
typedef __attribute__((ext_vector_type(16))) float f32x16;

#define B_SZ  16
#define NPTS  4096
#define MBLK  256                   // 4 waves per block        [R20: 512]
#define NFR   2                     // A fragments per wave     [R20: 1]
#define PRB   256                   // pred rows per block (64 per wave)
#define NCH   (NPTS / PRB)          // 16 row-chunks per (dir,b)
#define STGT  1024                  // targets per LDS stage
#define STILE (STGT / 32)           // 32 tiles per stage
#define NSTG  (NPTS / STGT)         // 4 stages
#define PPT   (STGT / MBLK)         // 4 points per thread per stage
#define NRT   (B_SZ * NPTS)         // 65536 rows per direction

__device__ __forceinline__ unsigned short f2bf(float f) {
    unsigned u = __float_as_uint(f);
    return (unsigned short)((u + 0x7FFFu + ((u >> 16) & 1u)) >> 16);
}
__device__ __forceinline__ float bf2f(unsigned short s) {
    return __uint_as_float(((unsigned)s) << 16);
}
__device__ __forceinline__ short n2(unsigned short s) {
    return (short)f2bf(-2.0f * bf2f(s));
}
// NOTE: no min3f inline-asm. R10/R13/R14 (asm min3 on MFMA results) failed;
// fminf-only rounds (R9/R11/R12/R15-R20) all passed. Never reintroduce.

// ---------------------------------------------------------------------------
// Fused single-kernel chamfer (R20-proven, 34.0us, absmax 0.0). ONE lever:
// NFR 1->2 — each ds_read_b128 B-fragment now feeds TWO MFMAs (wave owns 64
// rows), halving the DS pipe (the largest static pipe, ~10.2us/CU -> 5.1).
// Block shrinks to 4 waves (256 threads), grid unchanged (512 blocks,
// 2/CU). Staging math (dedupe + T14 issue-early), slot algebra, probe,
// R12-style 2-frag epilogue, block-sum: verbatim.
//  slot algebra: s0-2:-2ph·th s3-5:-2pl·th s6-8:-2ph·tl s9-11:-2pl·tl
//                s12,13:p2h,p2l s14,15:t2h,t2l   (exact split-bf16)
// ---------------------------------------------------------------------------
__global__ __launch_bounds__(MBLK, 2) void chamfer_fused(
    const float* __restrict__ pred, const float* __restrict__ target,
    float* __restrict__ out)
{
    __shared__ short8   sB[STILE * 64];   // 32 KB B fragments
    __shared__ unsigned rowOut[PRB];      // 1 KB final row-mins (uint bits)
    __shared__ float    red[MBLK / 64];

    const int dir = blockIdx.y;
    const float* own = dir ? target : pred;
    const float* opp = dir ? pred : target;

    const int b     = blockIdx.x >> 4;          // NCH = 16 chunks per batch
    const int chunk = blockIdx.x & (NCH - 1);
    const int tid   = threadIdx.x;
    const int lane  = tid & 63;
    const int w     = tid >> 6;                 // wave 0..3
    const int r32   = lane & 31;
    const int h     = lane >> 5;
    const short ONE = (short)0x3F80;

    // ---- A fragments: 2 x 32 own rows per wave (R12-verbatim math) ----
    short8 af[NFR];
    #pragma unroll
    for (int f = 0; f < NFR; ++f) {
        const float* pp = own +
            ((size_t)b*NPTS + chunk*PRB + w*64 + f*32 + r32)*3;
        float x = pp[0], y = pp[1], z = pp[2];
        unsigned short phx=f2bf(x), phy=f2bf(y), phz=f2bf(z);
        unsigned short plx=f2bf(x-bf2f(phx)), ply=f2bf(y-bf2f(phy)),
                       plz=f2bf(z-bf2f(phz));
        short8 v;
        if (h == 0) {
            v[0]=n2(phx); v[1]=n2(phy); v[2]=n2(phz);
            v[3]=n2(plx); v[4]=n2(ply); v[5]=n2(plz);
            v[6]=n2(phx); v[7]=n2(phy);
        } else {
            float p2 = fmaf(z,z,fmaf(y,y,x*x));
            unsigned short p2h=f2bf(p2), p2l=f2bf(p2-bf2f(p2h));
            v[0]=n2(phz); v[1]=n2(plx); v[2]=n2(ply); v[3]=n2(plz);
            v[4]=(short)p2h; v[5]=(short)p2l; v[6]=ONE; v[7]=ONE;
        }
        af[f] = v;
    }

    // ---- layout probe (verbatim) ----
    f32x16 zc;
    #pragma unroll
    for (int r = 0; r < 16; ++r) zc[r] = 0.0f;
    short8 mA = {0,0,0,0,0,0,0,0}, mB = {0,0,0,0,0,0,0,0};
    if (h == 0) { mA[0] = (short)f2bf((float)r32); mB[0] = ONE; }
    f32x16 pr = __builtin_amdgcn_mfma_f32_32x32x16_bf16(mA, mB, zc, 0, 0, 0);
    int lab[16];
    bool ok = true;
    #pragma unroll
    for (int r = 0; r < 16; ++r) {
        lab[r] = ((int)(pr[r] + 0.5f)) & 31;
        ok = ok && (lab[r] == ((r & 3) + 8 * (r >> 2) + 4 * h));
    }
    const bool fast = __all(ok) != 0;

    if (!fast) rowOut[tid] = 0x7F7F7F7Fu;  // slow-path sentinel

    // ---- scan ALL 4096 targets in 4 staged passes, T14 issue-early ----
    f32x16 rmin0, rmin1;
    #pragma unroll
    for (int r = 0; r < 16; ++r) { rmin0[r] = 1e30f; rmin1[r] = 1e30f; }

    const float* oppB = opp + (size_t)b * NPTS * 3;

    // prologue: raw loads for stage 0 (4 points per thread)
    float rx[PPT], ry[PPT], rz[PPT];
    #pragma unroll
    for (int j = 0; j < PPT; ++j) {
        const float* o = oppB + (size_t)(j * MBLK + tid) * 3;
        rx[j] = o[0]; ry[j] = o[1]; rz[j] = o[2];
    }

    for (int s = 0; s < NSTG; ++s) {
        __syncthreads();   // previous stage's compute done (sB free)
        // ---- convert raw -> BOTH fragment entries per point (verbatim) ----
        #pragma unroll
        for (int j = 0; j < PPT; ++j) {
            int p  = j * MBLK + tid;     // point within stage, 0..1023
            int t  = p >> 5, cc = p & 31;
            float tx = rx[j], ty = ry[j], tz = rz[j];
            unsigned short hx=f2bf(tx), hy=f2bf(ty), hz=f2bf(tz);
            unsigned short lx=f2bf(tx-bf2f(hx)), ly=f2bf(ty-bf2f(hy)),
                           lz=f2bf(tz-bf2f(hz));
            float t2 = fmaf(tz,tz,fmaf(ty,ty,tx*tx));
            unsigned short t2h=f2bf(t2), t2l=f2bf(t2-bf2f(t2h));
            short8 v0, v1;
            v0[0]=(short)hx; v0[1]=(short)hy; v0[2]=(short)hz;
            v0[3]=(short)hx; v0[4]=(short)hy; v0[5]=(short)hz;
            v0[6]=(short)lx; v0[7]=(short)ly;
            v1[0]=(short)lz; v1[1]=(short)lx; v1[2]=(short)ly;
            v1[3]=(short)lz; v1[4]=ONE; v1[5]=ONE;
            v1[6]=(short)t2h; v1[7]=(short)t2l;
            sB[t*64 + cc]      = v0;   // hh=0 half of tile t
            sB[t*64 + 32 + cc] = v1;   // hh=1 half of tile t
        }
        __syncthreads();

        // ---- T14: issue NEXT stage's raw loads before compute ----
        if (s + 1 < NSTG) {
            #pragma unroll
            for (int j = 0; j < PPT; ++j) {
                const float* o = oppB +
                    (size_t)((s + 1) * STGT + j * MBLK + tid) * 3;
                rx[j] = o[0]; ry[j] = o[1]; rz[j] = o[2];
            }
        }

        // ---- 32 tiles: 1 ds_read feeds 2 MFMAs (NFR=2) ----
        for (int t = 0; t < STILE; ++t) {
            short8 b0 = sB[t*64 + lane];
            f32x16 a0 = __builtin_amdgcn_mfma_f32_32x32x16_bf16(af[0], b0, zc, 0,0,0);
            f32x16 a1 = __builtin_amdgcn_mfma_f32_32x32x16_bf16(af[1], b0, zc, 0,0,0);
            #pragma unroll
            for (int r = 0; r < 16; ++r) {
                rmin0[r] = fminf(a0[r], rmin0[r]);
                rmin1[r] = fminf(a1[r], rmin1[r]);
            }
        }
    }

    // ---- row epilogue (R12-verbatim 2-frag): shfl fold, write by LABEL ----
    __syncthreads();   // also orders slow-path sentinel init
    if (fast) {
        #pragma unroll
        for (int r = 0; r < 16; ++r) {
            float v0 = rmin0[r];
            v0 = fminf(v0, __shfl_xor(v0, 1, 64));
            v0 = fminf(v0, __shfl_xor(v0, 2, 64));
            v0 = fminf(v0, __shfl_xor(v0, 4, 64));
            v0 = fminf(v0, __shfl_xor(v0, 8, 64));
            v0 = fminf(v0, __shfl_xor(v0, 16, 64));
            float v1 = rmin1[r];
            v1 = fminf(v1, __shfl_xor(v1, 1, 64));
            v1 = fminf(v1, __shfl_xor(v1, 2, 64));
            v1 = fminf(v1, __shfl_xor(v1, 4, 64));
            v1 = fminf(v1, __shfl_xor(v1, 8, 64));
            v1 = fminf(v1, __shfl_xor(v1, 16, 64));
            if (r32 == 0) {
                rowOut[w*64 +  0 + lab[r]] = __float_as_uint(v0);
                rowOut[w*64 + 32 + lab[r]] = __float_as_uint(v1);
            }
        }
    } else {
        #pragma unroll
        for (int r = 0; r < 16; ++r) {
            atomicMin(&rowOut[w*64 +  0 + lab[r]],
                      __float_as_uint(fmaxf(rmin0[r], 0.0f)));
            atomicMin(&rowOut[w*64 + 32 + lab[r]],
                      __float_as_uint(fmaxf(rmin1[r], 0.0f)));
        }
    }
    __syncthreads();

    // ---- block sum of the 256 complete row-mins -> one atomicAdd ----
    float v = __uint_as_float(rowOut[tid]);
    for (int off = 32; off > 0; off >>= 1)
        v += __shfl_down(v, off, 64);
    if ((tid & 63) == 0) red[w] = v;
    __syncthreads();
    if (tid == 0) {
        float s = 0.0f;
        #pragma unroll
        for (int i = 0; i < MBLK / 64; ++i) s += red[i];
        atomicAdd(out, s * (1.0f / (float)NRT));
    }
}

extern "C" void kernel_launch(void* const* d_in, const int* in_sizes, int n_in,
                              void* d_out, int out_size, void* d_ws, size_t ws_size,
                              hipStream_t stream) {
    const float* pred   = (const float*)d_in[0];
    const float* target = (const float*)d_in[1];
    float* out = (float*)d_out;

    hipMemsetAsync(out, 0, sizeof(float), stream);

    // grid: 16 batches x 16 chunks = 256 ; y = 2 directions ; 512 blocks
    dim3 grid(B_SZ * NCH, 2);
    chamfer_fused<<<grid, MBLK, 0, stream>>>(pred, target, out);
}

// Round 22
// 33.704 us; speedup vs baseline: 1.0537x; 1.0537x over previous
//
#include <hip/hip_runtime.h>

typedef __attribute__((ext_vector_type(8)))  short short8;
typedef __attribute__((ext_vector_type(16))) float f32x16;

#define B_SZ  16
#define NPTS  4096
#define MBLK  512                   // 8 waves per block
#define PRB   256                   // pred rows per block (32 per wave)
#define NCH   (NPTS / PRB)          // 16 row-chunks per (dir,b)
#define STGT  1024                  // targets per LDS stage
#define STILE (STGT / 32)           // 32 tiles per stage
#define NSTG  (NPTS / STGT)         // 4 stages
#define PPT   (STGT / MBLK)         // 2 points per thread per stage
#define NRT   (B_SZ * NPTS)         // 65536 rows per direction

__device__ __forceinline__ unsigned short f2bf(float f) {
    unsigned u = __float_as_uint(f);
    return (unsigned short)((u + 0x7FFFu + ((u >> 16) & 1u)) >> 16);
}
__device__ __forceinline__ float bf2f(unsigned short s) {
    return __uint_as_float(((unsigned)s) << 16);
}
__device__ __forceinline__ short n2(unsigned short s) {
    return (short)f2bf(-2.0f * bf2f(s));
}
// NOTE: no min3f inline-asm. R10/R13/R14 (asm min3 on MFMA results) failed;
// fminf-only rounds (R9/R11/R12/R15-R21) all passed. Never reintroduce.

// ---------------------------------------------------------------------------
// R20 SESSION-BEST, reverted byte-for-byte (34.0us total, absmax 0.0).
// R21's NFR=2 (halved DS, halved waves/SIMD) regressed to 35.5 — the kernel
// is latency/barrier-floored, not pipe-bound; 8 waves of occupancy beat DS
// savings. Structure: fused single kernel; each block = 256 complete rows
// (8 waves x 32); scans all 4096 targets in 4 stages (STGT=1024, 8
// barriers); T14 issue-early staging; deduped conversion (both fragment
// entries built by one thread); probe-guarded layout; complete row-mins ->
// block-sum -> ONE atomicAdd. No prep, no workspace, no combine.
//  slot algebra: s0-2:-2ph·th s3-5:-2pl·th s6-8:-2ph·tl s9-11:-2pl·tl
//                s12,13:p2h,p2l s14,15:t2h,t2l   (exact split-bf16)
// ---------------------------------------------------------------------------
__global__ __launch_bounds__(MBLK, 2) void chamfer_fused(
    const float* __restrict__ pred, const float* __restrict__ target,
    float* __restrict__ out)
{
    __shared__ short8   sB[STILE * 64];   // 32 KB B fragments
    __shared__ unsigned rowOut[PRB];      // 1 KB final row-mins (uint bits)
    __shared__ float    red[MBLK / 64];

    const int dir = blockIdx.y;
    const float* own = dir ? target : pred;
    const float* opp = dir ? pred : target;

    const int b     = blockIdx.x >> 4;          // NCH = 16 chunks per batch
    const int chunk = blockIdx.x & (NCH - 1);
    const int tid   = threadIdx.x;
    const int lane  = tid & 63;
    const int w     = tid >> 6;                 // wave 0..7
    const int r32   = lane & 31;
    const int h     = lane >> 5;
    const short ONE = (short)0x3F80;

    // ---- A fragment: this wave's 32 own rows ----
    short8 af;
    {
        const float* pp = own +
            ((size_t)b*NPTS + chunk*PRB + w*32 + r32)*3;
        float x = pp[0], y = pp[1], z = pp[2];
        unsigned short phx=f2bf(x), phy=f2bf(y), phz=f2bf(z);
        unsigned short plx=f2bf(x-bf2f(phx)), ply=f2bf(y-bf2f(phy)),
                       plz=f2bf(z-bf2f(phz));
        short8 v;
        if (h == 0) {
            v[0]=n2(phx); v[1]=n2(phy); v[2]=n2(phz);
            v[3]=n2(plx); v[4]=n2(ply); v[5]=n2(plz);
            v[6]=n2(phx); v[7]=n2(phy);
        } else {
            float p2 = fmaf(z,z,fmaf(y,y,x*x));
            unsigned short p2h=f2bf(p2), p2l=f2bf(p2-bf2f(p2h));
            v[0]=n2(phz); v[1]=n2(plx); v[2]=n2(ply); v[3]=n2(plz);
            v[4]=(short)p2h; v[5]=(short)p2l; v[6]=ONE; v[7]=ONE;
        }
        af = v;
    }

    // ---- layout probe ----
    f32x16 zc;
    #pragma unroll
    for (int r = 0; r < 16; ++r) zc[r] = 0.0f;
    short8 mA = {0,0,0,0,0,0,0,0}, mB = {0,0,0,0,0,0,0,0};
    if (h == 0) { mA[0] = (short)f2bf((float)r32); mB[0] = ONE; }
    f32x16 pr = __builtin_amdgcn_mfma_f32_32x32x16_bf16(mA, mB, zc, 0, 0, 0);
    int lab[16];
    bool ok = true;
    #pragma unroll
    for (int r = 0; r < 16; ++r) {
        lab[r] = ((int)(pr[r] + 0.5f)) & 31;
        ok = ok && (lab[r] == ((r & 3) + 8 * (r >> 2) + 4 * h));
    }
    const bool fast = __all(ok) != 0;

    if (!fast) rowOut[tid & (PRB - 1)] = 0x7F7F7F7Fu;  // slow-path sentinel

    // ---- scan ALL 4096 targets in 4 staged passes, T14 issue-early ----
    f32x16 rmin;
    #pragma unroll
    for (int r = 0; r < 16; ++r) rmin[r] = 1e30f;

    const float* oppB = opp + (size_t)b * NPTS * 3;

    // prologue: raw loads for stage 0 (2 points per thread)
    float rx[PPT], ry[PPT], rz[PPT];
    #pragma unroll
    for (int j = 0; j < PPT; ++j) {
        const float* o = oppB + (size_t)(j * MBLK + tid) * 3;
        rx[j] = o[0]; ry[j] = o[1]; rz[j] = o[2];
    }

    for (int s = 0; s < NSTG; ++s) {
        __syncthreads();   // previous stage's compute done (sB free)
        // ---- convert raw -> BOTH fragment entries per point ----
        #pragma unroll
        for (int j = 0; j < PPT; ++j) {
            int p  = j * MBLK + tid;     // point within stage, 0..1023
            int t  = p >> 5, cc = p & 31;
            float tx = rx[j], ty = ry[j], tz = rz[j];
            unsigned short hx=f2bf(tx), hy=f2bf(ty), hz=f2bf(tz);
            unsigned short lx=f2bf(tx-bf2f(hx)), ly=f2bf(ty-bf2f(hy)),
                           lz=f2bf(tz-bf2f(hz));
            float t2 = fmaf(tz,tz,fmaf(ty,ty,tx*tx));
            unsigned short t2h=f2bf(t2), t2l=f2bf(t2-bf2f(t2h));
            short8 v0, v1;
            v0[0]=(short)hx; v0[1]=(short)hy; v0[2]=(short)hz;
            v0[3]=(short)hx; v0[4]=(short)hy; v0[5]=(short)hz;
            v0[6]=(short)lx; v0[7]=(short)ly;
            v1[0]=(short)lz; v1[1]=(short)lx; v1[2]=(short)ly;
            v1[3]=(short)lz; v1[4]=ONE; v1[5]=ONE;
            v1[6]=(short)t2h; v1[7]=(short)t2l;
            sB[t*64 + cc]      = v0;   // hh=0 half of tile t
            sB[t*64 + 32 + cc] = v1;   // hh=1 half of tile t
        }
        __syncthreads();

        // ---- T14: issue NEXT stage's raw loads before compute ----
        if (s + 1 < NSTG) {
            #pragma unroll
            for (int j = 0; j < PPT; ++j) {
                const float* o = oppB +
                    (size_t)((s + 1) * STGT + j * MBLK + tid) * 3;
                rx[j] = o[0]; ry[j] = o[1]; rz[j] = o[2];
            }
        }

        // ---- 32 tiles: ds_read + MFMA + fmin fold ----
        for (int t = 0; t < STILE; ++t) {
            short8 b0 = sB[t*64 + lane];
            f32x16 a0 = __builtin_amdgcn_mfma_f32_32x32x16_bf16(af, b0, zc, 0,0,0);
            #pragma unroll
            for (int r = 0; r < 16; ++r)
                rmin[r] = fminf(a0[r], rmin[r]);
        }
    }

    // ---- row epilogue: shfl fold over 32 cols, COMPLETE mins -> rowOut ----
    __syncthreads();   // also orders slow-path sentinel init
    if (fast) {
        #pragma unroll
        for (int r = 0; r < 16; ++r) {
            float v0 = rmin[r];
            v0 = fminf(v0, __shfl_xor(v0, 1, 64));
            v0 = fminf(v0, __shfl_xor(v0, 2, 64));
            v0 = fminf(v0, __shfl_xor(v0, 4, 64));
            v0 = fminf(v0, __shfl_xor(v0, 8, 64));
            v0 = fminf(v0, __shfl_xor(v0, 16, 64));
            if (r32 == 0)   // lanes 0 and 32: 16 rows each, disjoint labels
                rowOut[w*32 + lab[r]] = __float_as_uint(v0);
        }
    } else {
        #pragma unroll
        for (int r = 0; r < 16; ++r)
            atomicMin(&rowOut[w*32 + lab[r]],
                      __float_as_uint(fmaxf(rmin[r], 0.0f)));
    }
    __syncthreads();

    // ---- block sum of the 256 complete row-mins -> one atomicAdd ----
    float v = (tid < PRB) ? __uint_as_float(rowOut[tid]) : 0.0f;
    for (int off = 32; off > 0; off >>= 1)
        v += __shfl_down(v, off, 64);
    if ((tid & 63) == 0) red[w] = v;
    __syncthreads();
    if (tid == 0) {
        float s = 0.0f;
        #pragma unroll
        for (int i = 0; i < MBLK / 64; ++i) s += red[i];
        atomicAdd(out, s * (1.0f / (float)NRT));
    }
}

extern "C" void kernel_launch(void* const* d_in, const int* in_sizes, int n_in,
                              void* d_out, int out_size, void* d_ws, size_t ws_size,
                              hipStream_t stream) {
    const float* pred   = (const float*)d_in[0];
    const float* target = (const float*)d_in[1];
    float* out = (float*)d_out;

    hipMemsetAsync(out, 0, sizeof(float), stream);

    // grid: 16 batches x 16 chunks = 256 ; y = 2 directions ; 512 blocks
    dim3 grid(B_SZ * NCH, 2);
    chamfer_fused<<<grid, MBLK, 0, stream>>>(pred, target, out);
}